// Round 6
// baseline (250.608 us; speedup 1.0000x reference)
//
#include <hip/hip_runtime.h>
#include <math.h>

#define B      32
#define CIN    128
#define NN     8192
#define N1     8190    // output length after k=3 valid conv
#define CH     10
#define TOUT   244     // diag outputs per block
#define NTILE  34      // ceil(8190/244)
#define SCOLS  256     // staged signal cols per channel row (1024 B = one wave-wide lds load)
#define CPC    16      // channels per chunk
#define NCHUNK (CIN / CPC)

// Async global->LDS, 16B per lane: LDS dest = wave-uniform base + lane*16.
__device__ __forceinline__ void load_lds16(const float* g, float* l)
{
    __builtin_amdgcn_global_load_lds(
        (const __attribute__((address_space(1))) void*)g,
        (__attribute__((address_space(3))) void*)l, 16, 0, 0);
}

// K0: transpose w1[o][ci][k] -> wT[ci][o*3+k] (rows padded to 32 floats)
// so k_main's per-channel 30 weights are contiguous wave-uniform s_loads.
__global__ void k0_prep(const float* __restrict__ w1, float* __restrict__ wT)
{
    const int i = blockIdx.x * 256 + threadIdx.x;     // 0..4095
    if (i < CIN * 32) {
        const int ci = i >> 5, r = i & 31;
        float v = 0.f;
        if (r < 30) {
            const int o = r / 3, k = r - o * 3;
            v = w1[(o * CIN + ci) * 3 + k];
        }
        wT[i] = v;
    }
}

// K_MAIN: whole pipeline per 244-output tile.
// Phase 1: stream signal via async global_load_lds (16 rows x 1KB per chunk,
//          zero VGPR cost -> compiler cannot re-roll the MLP), accumulate
//          conv1 into y[10] from LDS.
// Phase 2: conv2 -> h2s (LDS); convT+relu+1x1+sigmoid -> lsh/rsh; tridiag+log;
//          block sum.
__global__ __launch_bounds__(256, 4) void k_main(
    const float* __restrict__ sig, const float* __restrict__ wT,
    const float* __restrict__ b1, const float* __restrict__ w2, const float* __restrict__ b2,
    const float* __restrict__ wt, const float* __restrict__ bt,
    const float* __restrict__ w3, const float* __restrict__ b3,
    const float* __restrict__ cd, const float* __restrict__ cstp,
    float* __restrict__ outv, float* __restrict__ bsums)
{
    __shared__ float sigb[CPC * SCOLS];   // 16 KB staging buffer
    __shared__ float h2s[CH * 256];       // 10 KB
    __shared__ float lsh[256], rsh[256], red[256];

    const int tid  = threadIdx.x;
    const int lane = tid & 63;
    const int wv   = tid >> 6;            // wave id 0..3
    const int b    = blockIdx.y;
    const int t0   = blockIdx.x * TOUT;

    int s0 = t0 - 4;                      // staged window base (16B-aligned)
    if (s0 < 0) s0 = 0;
    if (s0 > NN - SCOLS) s0 = NN - SCOLS;
    const int d0 = t0 - s0;               // 0 (block 0), 4 (normal), 116 (last)

    // per-lane global base: lane covers bytes [lane*16, lane*16+16) of each row
    const float* gb = sig + (size_t)b * CIN * NN + s0 + lane * 4;

    const int tc = (tid < 254) ? tid : 253;   // clamp so LDS reads stay in range

    float y[CH];
#pragma unroll
    for (int o = 0; o < CH; ++o) y[o] = b1[o];

    for (int c = 0; c < NCHUNK; ++c) {
        if (c) __syncthreads();           // prior chunk fully consumed before overwrite
#pragma unroll
        for (int r = 0; r < 4; ++r) {     // this wave stages rows wv*4 .. wv*4+3
            const int ch = c * CPC + wv * 4 + r;
            load_lds16(gb + (size_t)ch * NN, &sigb[(wv * 4 + r) * SCOLS]);
        }
        __syncthreads();                  // vmcnt drained by compiler before barrier

        const float* wbase = wT + c * CPC * 32;
#pragma unroll
        for (int j = 0; j < CPC; ++j) {
            const float v0 = sigb[j * SCOLS + tc];
            const float v1 = sigb[j * SCOLS + tc + 1];
            const float v2 = sigb[j * SCOLS + tc + 2];
            const float* wrow = wbase + j * 32;   // 30 contiguous uniform weights
#pragma unroll
            for (int o = 0; o < CH; ++o) {
                y[o] = fmaf(wrow[o * 3 + 0], v0, y[o]);
                y[o] = fmaf(wrow[o * 3 + 1], v1, y[o]);
                y[o] = fmaf(wrow[o * 3 + 2], v2, y[o]);
            }
        }
    }

    // conv2 (1x1) + relu -> h2s; column g = s0 + tid (zero outside [0,N1))
    const int g = s0 + tid;
#pragma unroll
    for (int o = 0; o < CH; ++o) y[o] = fmaxf(y[o], 0.f);
#pragma unroll
    for (int o = 0; o < CH; ++o) {
        float a = b2[o];
#pragma unroll
        for (int i = 0; i < CH; ++i) a = fmaf(w2[o * CH + i], y[i], a);
        h2s[o * 256 + tid] = (tid <= 253 && g < N1) ? fmaxf(a, 0.f) : 0.f;
    }
    __syncthreads();

    // convT(k=3) + relu + 1x1 + sigmoid -> lr at s = t0 + tid
    const int s = t0 + tid;
    if (tid <= TOUT + 2 && s < NN) {
        const int ib = tid + d0 - 2;      // LDS col of h2[s-2]
        float acc[CH];
#pragma unroll
        for (int o = 0; o < CH; ++o) acc[o] = bt[o];
#pragma unroll
        for (int i = 0; i < CH; ++i) {
            const float a0 = (ib >= 0)     ? h2s[i * 256 + ib]     : 0.f;  // h2[s-2]
            const float a1 = (ib + 1 >= 0) ? h2s[i * 256 + ib + 1] : 0.f;  // h2[s-1]
            const float a2 =                 h2s[i * 256 + ib + 2];        // h2[s]
            const float* wp = wt + i * CH * 3;
#pragma unroll
            for (int o = 0; o < CH; ++o) {
                acc[o] = fmaf(wp[o * 3 + 0], a2, acc[o]);
                acc[o] = fmaf(wp[o * 3 + 1], a1, acc[o]);
                acc[o] = fmaf(wp[o * 3 + 2], a0, acc[o]);
            }
        }
        float l = b3[0], r = b3[1];
#pragma unroll
        for (int o = 0; o < CH; ++o) {
            const float h3 = fmaxf(acc[o], 0.f);
            l = fmaf(w3[o],      h3, l);
            r = fmaf(w3[CH + o], h3, r);
        }
        lsh[tid] = 1.f / (1.f + __expf(-l));
        rsh[tid] = 1.f / (1.f + __expf(-r));
    }
    __syncthreads();

    // tridiagonal update + log for t = t0 + tid
    float vlog = 0.f;
    const int t = t0 + tid;
    if (tid < TOUT && t < N1) {
        const float c0 = cd[(size_t)b * (NN - 1) + t];
        const float c1 = cd[(size_t)b * (NN - 1) + t + 1];
        const float mi = c1 * rsh[tid + 1] + c0 * lsh[tid + 1];
        const float mo = rsh[tid] + lsh[tid + 2];
        vlog = __logf(cstp[0] * mi / mo);
        outv[(size_t)b * N1 + t] = vlog;
    }

    red[tid] = vlog;
    __syncthreads();
#pragma unroll
    for (int st = 128; st > 0; st >>= 1) {
        if (tid < st) red[tid] += red[tid + st];
        __syncthreads();
    }
    if (tid == 0) bsums[blockIdx.y * NTILE + blockIdx.x] = red[0];
}

// K3: every block redundantly reduces the 1088 bsums (L2-hot), subtracts mean.
__global__ __launch_bounds__(256) void k3_meansub(
    const float* __restrict__ bsums, float* __restrict__ outv, int n)
{
    __shared__ float red[256];
    const int tid = threadIdx.x;
    float s = 0.f;
    for (int i = tid; i < NTILE * B; i += 256) s += bsums[i];
    red[tid] = s;
    __syncthreads();
#pragma unroll
    for (int st = 128; st > 0; st >>= 1) {
        if (tid < st) red[tid] += red[tid + st];
        __syncthreads();
    }
    const float mean = red[0] / (float)(B * N1);
    __syncthreads();
    const int i = blockIdx.x * 256 + tid;
    if (i < n) outv[i] -= mean;
}

extern "C" void kernel_launch(void* const* d_in, const int* in_sizes, int n_in,
                              void* d_out, int out_size, void* d_ws, size_t ws_size,
                              hipStream_t stream)
{
    const float* sig = (const float*)d_in[0];
    const float* cd  = (const float*)d_in[1];
    // d_in[2] = index_diag (1 for these shapes)
    const float* w1  = (const float*)d_in[3];
    const float* b1  = (const float*)d_in[4];
    const float* w2  = (const float*)d_in[5];
    const float* b2  = (const float*)d_in[6];
    const float* wt  = (const float*)d_in[7];
    const float* bt  = (const float*)d_in[8];
    const float* w3  = (const float*)d_in[9];
    const float* b3  = (const float*)d_in[10];
    const float* cst = (const float*)d_in[11];

    float* outv = (float*)d_out;

    // workspace layout (floats)
    float* ws   = (float*)d_ws;
    float* wT   = ws;                  // CIN*32 = 4096
    float* bsum = wT + CIN * 32;       // NTILE*B = 1088

    dim3 blk(256);

    k0_prep   <<<dim3(16), blk, 0, stream>>>(w1, wT);
    k_main    <<<dim3(NTILE, B), blk, 0, stream>>>(sig, wT, b1, w2, b2,
                                                   wt, bt, w3, b3, cd, cst, outv, bsum);
    k3_meansub<<<dim3((out_size + 255) / 256), blk, 0, stream>>>(bsum, outv, out_size);
}

// Round 7
// 250.465 us; speedup vs baseline: 1.0006x; 1.0006x over previous
//
#include <hip/hip_runtime.h>
#include <math.h>

#define B      32
#define CIN    128
#define NN     8192
#define N1     8190    // output length after k=3 valid conv
#define CH     10
#define TOUT   252     // diag outputs per block (h2 tile = 256 cols, 1/thread)
#define NTILE  33      // ceil(8190/252); last tile overlaps, sum is ownership-masked
#define WR     72      // staged floats per channel row per wave (64 + halo + clamp slack)
#define CPR    8       // channels per chunk
#define NCHUNK (CIN / CPR)   // 16

// Async global->LDS, 4B per lane: LDS dest = wave-uniform base + lane*4.
__device__ __forceinline__ void load_lds4(const float* g, float* l)
{
    __builtin_amdgcn_global_load_lds(
        (const __attribute__((address_space(1))) void*)g,
        (__attribute__((address_space(3))) void*)l, 4, 0, 0);
}

// K0: transpose w1[o][ci][k] -> wT[ci][o*3+k] (rows padded to 32 floats)
__global__ void k0_prep(const float* __restrict__ w1, float* __restrict__ wT)
{
    const int i = blockIdx.x * 256 + threadIdx.x;     // 0..4095
    if (i < CIN * 32) {
        const int ci = i >> 5, r = i & 31;
        float v = 0.f;
        if (r < 30) {
            const int o = r / 3, k = r - o * 3;
            v = w1[(o * CIN + ci) * 3 + k];
        }
        wT[i] = v;
    }
}

// K_MAIN: wave-private barrier-free streaming conv1 pipeline + fused tail.
__global__ __launch_bounds__(256, 5) void k_main(
    const float* __restrict__ sig, const float* __restrict__ wT,
    const float* __restrict__ b1, const float* __restrict__ w2, const float* __restrict__ b2,
    const float* __restrict__ wt, const float* __restrict__ bt,
    const float* __restrict__ w3, const float* __restrict__ b3,
    const float* __restrict__ cd, const float* __restrict__ cstp,
    float* __restrict__ outv, float* __restrict__ bsums)
{
    __shared__ float stg[4][2][CPR * WR];   // 18432 B, wave-private double buffers
    __shared__ float h2s[CH * 256];         // 10240 B
    __shared__ float lsh[256], rsh[256], red[256];

    const int tid  = threadIdx.x;
    const int lane = tid & 63;
    const int wv   = tid >> 6;
    const int b    = blockIdx.y;

    int t0 = blockIdx.x * TOUT;
    if (t0 > N1 - TOUT) t0 = N1 - TOUT;     // last tile overlaps previous

    const int  g      = t0 - 2 + tid;       // this thread's h2 column
    const bool gvalid = (g >= 0) && (g < N1);

    // wave-private staged window: signal floats [lb, lb+WR)
    const int gw0 = t0 - 2 + 64 * wv;
    int lb = gw0;
    if (lb < 0) lb = 0;
    if (lb > NN - WR) lb = NN - WR;
    const int dlt = gw0 - lb;               // -2 (bx=0,wv=0), 0, or 8 (last tile, wv=3)
    int ib = lane + dlt;                    // buffer index of signal[g]
    if (ib < 0) ib = 0;
    if (ib > WR - 3) ib = WR - 3;           // clamped lanes are masked by gvalid

    const float* grow = sig + (size_t)b * CIN * NN + lb + lane;  // per-lane base
    float* buf0 = &stg[wv][0][0];
    float* buf1 = &stg[wv][1][0];

    float y[CH];
#pragma unroll
    for (int o = 0; o < CH; ++o) y[o] = b1[o];

    auto issue = [&](int c, float* bf) {
#pragma unroll
        for (int r = 0; r < CPR; ++r) {
            const float* gp = grow + (size_t)(c * CPR + r) * NN;
            load_lds4(gp,     bf + r * WR);       // buffer floats [0,64)
            load_lds4(gp + 8, bf + r * WR + 8);   // buffer floats [8,72) (overlap identical)
        }
    };
    auto consume = [&](int c, const float* bf) {
        const float* wbase = wT + c * CPR * 32;
#pragma unroll
        for (int r = 0; r < CPR; ++r) {
            const float v0 = bf[r * WR + ib];
            const float v1 = bf[r * WR + ib + 1];
            const float v2 = bf[r * WR + ib + 2];
            const float* wrow = wbase + r * 32;   // 30 contiguous wave-uniform weights
#pragma unroll
            for (int o = 0; o < CH; ++o) {
                y[o] = fmaf(wrow[o * 3 + 0], v0, y[o]);
                y[o] = fmaf(wrow[o * 3 + 1], v1, y[o]);
                y[o] = fmaf(wrow[o * 3 + 2], v2, y[o]);
            }
        }
    };

    // wave-private software pipeline: chunk c+1's 16 loads in flight while
    // consuming chunk c; no __syncthreads in the K-loop.
    issue(0, buf0);
    for (int c = 0; c < NCHUNK; ++c) {
        float* cur = (c & 1) ? buf1 : buf0;
        float* nxt = (c & 1) ? buf0 : buf1;
        if (c + 1 < NCHUNK) {
            issue(c + 1, nxt);
            __builtin_amdgcn_s_waitcnt(0x4F70);   // vmcnt(16): old chunk arrived
        } else {
            __builtin_amdgcn_s_waitcnt(0x0F70);   // vmcnt(0): final chunk
        }
        consume(c, cur);
    }

    // conv2 (1x1) + relu -> h2s (zero outside [0,N1) for convT zero-padding)
#pragma unroll
    for (int o = 0; o < CH; ++o) y[o] = fmaxf(y[o], 0.f);
#pragma unroll
    for (int o = 0; o < CH; ++o) {
        float a = b2[o];
#pragma unroll
        for (int i = 0; i < CH; ++i) a = fmaf(w2[o * CH + i], y[i], a);
        h2s[o * 256 + tid] = gvalid ? fmaxf(a, 0.f) : 0.f;
    }
    __syncthreads();

    // convT(k=3) + relu + 1x1 + sigmoid -> lr at s = t0 + tid  (tid <= 253)
    if (tid <= 253) {
        float acc[CH];
#pragma unroll
        for (int o = 0; o < CH; ++o) acc[o] = bt[o];
#pragma unroll
        for (int i = 0; i < CH; ++i) {
            const float a0 = h2s[i * 256 + tid];      // h2[s-2]
            const float a1 = h2s[i * 256 + tid + 1];  // h2[s-1]
            const float a2 = h2s[i * 256 + tid + 2];  // h2[s]
            const float* wp = wt + i * CH * 3;
#pragma unroll
            for (int o = 0; o < CH; ++o) {
                acc[o] = fmaf(wp[o * 3 + 0], a2, acc[o]);
                acc[o] = fmaf(wp[o * 3 + 1], a1, acc[o]);
                acc[o] = fmaf(wp[o * 3 + 2], a0, acc[o]);
            }
        }
        float l = b3[0], r = b3[1];
#pragma unroll
        for (int o = 0; o < CH; ++o) {
            const float h3 = fmaxf(acc[o], 0.f);
            l = fmaf(w3[o],      h3, l);
            r = fmaf(w3[CH + o], h3, r);
        }
        lsh[tid] = 1.f / (1.f + __expf(-l));
        rsh[tid] = 1.f / (1.f + __expf(-r));
    }
    __syncthreads();

    // tridiagonal update + log for t = t0 + tid  (tid < TOUT; always t < N1)
    float vlog = 0.f;
    bool  owned = false;
    const int t = t0 + tid;
    if (tid < TOUT) {
        const float c0 = cd[(size_t)b * (NN - 1) + t];
        const float c1 = cd[(size_t)b * (NN - 1) + t + 1];
        const float mi = c1 * rsh[tid + 1] + c0 * lsh[tid + 1];
        const float mo = rsh[tid] + lsh[tid + 2];
        vlog = __logf(cstp[0] * mi / mo);
        outv[(size_t)b * N1 + t] = vlog;             // overlap writes are identical
        owned = (t >= blockIdx.x * TOUT);            // mask overlap out of the sum
    }

    red[tid] = owned ? vlog : 0.f;
    __syncthreads();
#pragma unroll
    for (int st = 128; st > 0; st >>= 1) {
        if (tid < st) red[tid] += red[tid + st];
        __syncthreads();
    }
    if (tid == 0) bsums[blockIdx.y * NTILE + blockIdx.x] = red[0];
}

// K3: every block redundantly reduces the 1056 bsums (L2-hot), subtracts mean.
__global__ __launch_bounds__(256) void k3_meansub(
    const float* __restrict__ bsums, float* __restrict__ outv, int n)
{
    __shared__ float red[256];
    const int tid = threadIdx.x;
    float s = 0.f;
    for (int i = tid; i < NTILE * B; i += 256) s += bsums[i];
    red[tid] = s;
    __syncthreads();
#pragma unroll
    for (int st = 128; st > 0; st >>= 1) {
        if (tid < st) red[tid] += red[tid + st];
        __syncthreads();
    }
    const float mean = red[0] / (float)(B * N1);
    __syncthreads();
    const int i = blockIdx.x * 256 + tid;
    if (i < n) outv[i] -= mean;
}

extern "C" void kernel_launch(void* const* d_in, const int* in_sizes, int n_in,
                              void* d_out, int out_size, void* d_ws, size_t ws_size,
                              hipStream_t stream)
{
    const float* sig = (const float*)d_in[0];
    const float* cd  = (const float*)d_in[1];
    // d_in[2] = index_diag (1 for these shapes)
    const float* w1  = (const float*)d_in[3];
    const float* b1  = (const float*)d_in[4];
    const float* w2  = (const float*)d_in[5];
    const float* b2  = (const float*)d_in[6];
    const float* wt  = (const float*)d_in[7];
    const float* bt  = (const float*)d_in[8];
    const float* w3  = (const float*)d_in[9];
    const float* b3  = (const float*)d_in[10];
    const float* cst = (const float*)d_in[11];

    float* outv = (float*)d_out;

    // workspace layout (floats)
    float* ws   = (float*)d_ws;
    float* wT   = ws;                  // CIN*32 = 4096
    float* bsum = wT + CIN * 32;       // NTILE*B = 1056

    dim3 blk(256);

    k0_prep   <<<dim3(16), blk, 0, stream>>>(w1, wT);
    k_main    <<<dim3(NTILE, B), blk, 0, stream>>>(sig, wT, b1, w2, b2,
                                                   wt, bt, w3, b3, cd, cst, outv, bsum);
    k3_meansub<<<dim3((out_size + 255) / 256), blk, 0, stream>>>(bsum, outv, out_size);
}